// Round 9
// baseline (325.573 us; speedup 1.0000x reference)
//
#include <hip/hip_runtime.h>
#include <stdint.h>

#define B_ 2
#define S_ 2048
#define H_ 12
#define D_ 64
#define HD_ 768
#define KEEP_HI 3865470464u           // 7549747u << 9 : bits < this  <=>  uniform < 0.9
#define C_INIT 0.15200309344504997f   // log2(1/0.9), folded into MFMA C-init
#define QSCALE 0.18033688011112042f   // 0.125 * log2(e)

typedef __attribute__((ext_vector_type(8))) _Float16 f16x8;
typedef __attribute__((ext_vector_type(4))) _Float16 f16x4;
typedef __attribute__((ext_vector_type(4))) float f32x4;

#define MFMA32 __builtin_amdgcn_mfma_f32_16x16x32_f16   // K=32, A/B = f16x8
#define MFMA16 __builtin_amdgcn_mfma_f32_16x16x16f16    // K=16, A/B = f16x4

// JAX partitionable threefry, key (0,42), counter (0,i), out = x0^x1.
// (bit-exact verified rounds 2-8)
__device__ __forceinline__ uint32_t tf_bits(uint32_t i) {
    const uint32_t k1 = 42u, k2 = 0x1BD11BF0u;
    uint32_t x0 = 0u, x1 = i + k1;
#define TF_R(r) { x0 += x1; x1 = __builtin_rotateleft32(x1, (r)); x1 ^= x0; }
    TF_R(13) TF_R(15) TF_R(26) TF_R(6)
    x0 += k1; x1 += k2 + 1u;
    TF_R(17) TF_R(29) TF_R(16) TF_R(24)
    x0 += k2; x1 += 2u;
    TF_R(13) TF_R(15) TF_R(26) TF_R(6)
    x1 += k1 + 3u;
    TF_R(17) TF_R(29) TF_R(16) TF_R(24)
    x0 += k1; x1 += k2 + 4u;
    TF_R(13) TF_R(15) TF_R(26) TF_R(6)
    x0 += k2; x1 += 5u;
#undef TF_R
    return x0 ^ x1;
}

// Wave-autonomous flash attention + dropout. NO shared memory, NO barriers:
// every wave owns 16 q-rows, streams K/V fragments straight from L1/L2.
template<int HALVES>
__global__ __launch_bounds__(256, 4)
void attn_kernel(const float* __restrict__ Q, const float* __restrict__ K,
                 const float* __restrict__ V, float* __restrict__ O,
                 float* __restrict__ W) {
    constexpr int NT = 32 / HALVES;
    const int tid  = threadIdx.x;
    const int lane = tid & 63;
    const int g    = lane >> 4;
    const int sl   = lane & 15;

    const int gw   = blockIdx.x * 4 + (tid >> 6);          // global wave id
    const int half = (HALVES == 2) ? (gw / 3072) : 0;
    const int rem  = (HALVES == 2) ? (gw % 3072) : gw;
    const int bh   = rem >> 7;                             // 0..23
    const int sg   = rem & 127;                            // 16-row group
    const int h    = bh % H_;
    const int b    = bh / H_;
    const int sbase = sg * 16;
    const int s    = sbase + sl;
    const int kt0  = half * NT;

    const size_t kvbase = (size_t)b * S_ * HD_ + (size_t)h * D_;

    // ---- Q fragment (B-operand of QK), scale 0.125*log2e, fp16 hi/lo ----
    f16x8 qh[2], ql[2];
    {
        const float* qp = Q + ((size_t)(b * S_ + s) * H_ + h) * D_;
#pragma unroll
        for (int ks = 0; ks < 2; ++ks) {
            int d0 = 32 * ks + 8 * g;
            float4 f0 = *reinterpret_cast<const float4*>(qp + d0);
            float4 f1 = *reinterpret_cast<const float4*>(qp + d0 + 4);
            float ff[8] = {f0.x, f0.y, f0.z, f0.w, f1.x, f1.y, f1.z, f1.w};
#pragma unroll
            for (int j = 0; j < 8; ++j) {
                float f = ff[j] * QSCALE;
                _Float16 hi = (_Float16)f;
                qh[ks][j] = hi;
                ql[ks][j] = (_Float16)(f - (float)hi);
            }
        }
    }

    float lrun = 0.f;
    f32x4 outacc[4];   // outacc[nb][jj] = out[s = sbase+4g+jj][dd = 16nb+sl]
#pragma unroll
    for (int nb = 0; nb < 4; ++nb) outacc[nb] = (f32x4){0.f, 0.f, 0.f, 0.f};

    const uint32_t rowbase = ((uint32_t)(bh * S_ + s)) << 11;

    for (int ktl = 0; ktl < NT; ++ktl) {
        const int ktg = kt0 + ktl;
        const float* kb = K + kvbase + (size_t)(ktg * 64) * HD_;
        const float* vb = V + kvbase + (size_t)(ktg * 64) * HD_;

        // ---- QK^T (swapped): K A-frag direct from global, fp32 -> f16 hi ----
        // sc[m][r] = log2e*S^T[t][s] + C, t = 16m+4g+r, s = sl
        f32x4 sc[4];
#pragma unroll
        for (int m = 0; m < 4; ++m) sc[m] = (f32x4){C_INIT, C_INIT, C_INIT, C_INIT};
#pragma unroll
        for (int m = 0; m < 4; ++m) {
            const float* kp = kb + (16 * m + sl) * HD_ + 8 * g;
#pragma unroll
            for (int ks = 0; ks < 2; ++ks) {
                float4 a0 = *reinterpret_cast<const float4*>(kp + 32 * ks);
                float4 a1 = *reinterpret_cast<const float4*>(kp + 32 * ks + 4);
                f16x8 ah;
                ah[0] = (_Float16)a0.x; ah[1] = (_Float16)a0.y;
                ah[2] = (_Float16)a0.z; ah[3] = (_Float16)a0.w;
                ah[4] = (_Float16)a1.x; ah[5] = (_Float16)a1.y;
                ah[6] = (_Float16)a1.z; ah[7] = (_Float16)a1.w;
                sc[m] = MFMA32(ah, qh[ks], sc[m], 0, 0, 0);
                sc[m] = MFMA32(ah, ql[ks], sc[m], 0, 0, 0);
            }
        }

        // ---- fused exp2 + threefry dropout + fp16 pack ----
        // w[m] is EXACTLY the 16x16x16 A-frag of P: row=sl, k=4g+r (block m)
        const uint32_t fb = rowbase + (uint32_t)(ktg * 64);
        f16x4 w[4];
#pragma unroll
        for (int m = 0; m < 4; ++m) {
            int t0 = 16 * m + 4 * g;
#pragma unroll
            for (int r = 0; r < 4; ++r) {
                float e = exp2f(sc[m][r]);          // = exp(score)/0.9
                lrun += e;
                uint32_t bits = tf_bits(fb + (uint32_t)(t0 + r));
                float pf = (bits < KEEP_HI) ? e : 0.0f;
                w[m][r] = (_Float16)pf;             // RNE fp16 = astype(f16)
            }
        }

        // ---- AV: A = P (regs), B = V natural [t][dd] from global ----
#pragma unroll
        for (int m = 0; m < 4; ++m) {
            const float* vrow = vb + (16 * m + 4 * g) * HD_ + sl;
#pragma unroll
            for (int nb = 0; nb < 4; ++nb) {
                f16x4 vf;
#pragma unroll
                for (int r = 0; r < 4; ++r)
                    vf[r] = (_Float16)vrow[r * HD_ + 16 * nb];
                outacc[nb] = MFMA16(w[m], vf, outacc[nb], 0, 0, 0);
            }
        }
    }

    // ---- row-sum L across the 4 lane groups (replicated after 2 shuffles) ----
    lrun += __shfl_xor(lrun, 16);
    lrun += __shfl_xor(lrun, 32);

    if (HALVES == 1) {
        float* ob = O + ((size_t)bh * S_ + sbase) * D_;
#pragma unroll
        for (int jj = 0; jj < 4; ++jj) {
            float invL = 1.0f / (0.9f * __shfl(lrun, 4 * g + jj));  // row 4g+jj
#pragma unroll
            for (int nb = 0; nb < 4; ++nb)
                ob[(size_t)(4 * g + jj) * D_ + 16 * nb + sl] = outacc[nb][jj] * invL;
        }
    } else {
        float* wbase = W + ((size_t)(half * 24 + bh) * S_ + sbase) * 68;
#pragma unroll
        for (int jj = 0; jj < 4; ++jj) {
#pragma unroll
            for (int nb = 0; nb < 4; ++nb)
                wbase[(4 * g + jj) * 68 + 16 * nb + sl] = outacc[nb][jj];
        }
        if (g == 0) wbase[sl * 68 + 64] = lrun;   // row sbase+sl partial L
    }
}

__global__ __launch_bounds__(256)
void combine_kernel(const float* __restrict__ W, float* __restrict__ O) {
    const int row = blockIdx.x * 4 + (threadIdx.x >> 6);   // bh*2048 + s
    const int dd  = threadIdx.x & 63;
    const float* w0 = W + (size_t)row * 68;
    const float* w1 = W + ((size_t)(24 * 2048) + row) * 68;
    const float L = w0[64] + w1[64];                        // = L_true/0.9
    const float scale = 1.0f / (0.9f * L);
    O[(size_t)row * 64 + dd] = (w0[dd] + w1[dd]) * scale;
}

extern "C" void kernel_launch(void* const* d_in, const int* in_sizes, int n_in,
                              void* d_out, int out_size, void* d_ws, size_t ws_size,
                              hipStream_t stream) {
    const float* Q = (const float*)d_in[0];
    const float* K = (const float*)d_in[1];
    const float* V = (const float*)d_in[2];
    float* O = (float*)d_out;
    (void)in_sizes; (void)n_in; (void)out_size;

    const size_t ws_need = (size_t)2 * 24 * 2048 * 68 * sizeof(float);  // 26.7 MB
    if (d_ws && ws_size >= ws_need) {
        float* W = (float*)d_ws;
        attn_kernel<2><<<dim3(1536), dim3(256), 0, stream>>>(Q, K, V, O, W);
        combine_kernel<<<dim3(24 * 2048 / 4), dim3(256), 0, stream>>>(W, O);
    } else {
        attn_kernel<1><<<dim3(768), dim3(256), 0, stream>>>(Q, K, V, O, nullptr);
    }
}